// Round 10
// baseline (2700.140 us; speedup 1.0000x reference)
//
#include <hip/hip_runtime.h>

// SineNet: fc1 -> LSTM(sine) -> proj.  B=64 T=1024 I=128 H=512 4H=2048 NS=32
// Round 10: K-split gate GEMM, A-fragments polled DIRECTLY into registers.
//  - 16 gangs x 16 WGs (gang=bid>>4), 4 batches/gang; tagged-packet protocol
//    of R9 (packet = {f16 h | (t+1)<<16}, sc0 sc1, ring depth 2) unchanged.
//  - Wave wv owns K-chunk [64wv,64wv+64) x all 128 cols: B-frags 64 VGPR.
//    Its A-frag slice = 1KB of packets: lanes l15<4 poll 4x dwordx4 straight
//    into regs, extract, 16 reg-fed MFMAs. No h LDS restage, no B3, no GEMM
//    ds_reads. Cross-wave K-reduction via pgat[8][4][132] summed in cell.
//  - hop: small tag-polled h copy (waves 2-3, shadow) feeds out-proj; out
//    stores lag 3 steps, drained in epilogue.
//  - 2 barriers/step: B1 (pgat/hop ready), B2 (cell read done, pre next).

constexpr int Bb = 64;
constexpr int Tt = 1024;
constexpr int Ii = 128;
constexpr int Hh = 512;
constexpr int G4 = 2048;
constexpr int NS = 32;
constexpr int NG = 16;   // gangs
constexpr int GW = 16;   // WGs per gang
constexpr int BPG = 4;   // batches per gang

typedef _Float16 h2 __attribute__((ext_vector_type(2)));
typedef _Float16 h8 __attribute__((ext_vector_type(8)));
typedef float    f4 __attribute__((ext_vector_type(4)));
typedef unsigned int u32;
typedef u32 u32x4 __attribute__((ext_vector_type(4)));

__device__ __forceinline__ float dot8(h8 w, h8 x, float acc) {
  h2 w0 = {w[0], w[1]}, w1 = {w[2], w[3]}, w2 = {w[4], w[5]}, w3 = {w[6], w[7]};
  h2 x0 = {x[0], x[1]}, x1 = {x[2], x[3]}, x2 = {x[4], x[5]}, x3 = {x[6], x[7]};
  acc = __builtin_amdgcn_fdot2(x0, w0, acc, false);
  acc = __builtin_amdgcn_fdot2(x1, w1, acc, false);
  acc = __builtin_amdgcn_fdot2(x2, w2, acc, false);
  acc = __builtin_amdgcn_fdot2(x3, w3, acc, false);
  return acc;
}

__device__ __forceinline__ float sigf(float x) { return 1.f / (1.f + __expf(-x)); }

// ---- Wc = W1@W_ih (fp32) -> f16 B-frags (N-split, unchanged from R9) ------
__global__ void k_wc(const float* __restrict__ W1, const float* __restrict__ Wih,
                     const float* __restrict__ b1, const float* __restrict__ bl,
                     _Float16* __restrict__ Wc4, float* __restrict__ bias2) {
  const int j = blockIdx.x;   // global gate col 0..2047
  const int i = threadIdx.x;  // k index 0..127
  __shared__ float col[Hh];
  __shared__ float part[128];
  for (int k = i; k < Hh; k += 128) col[k] = Wih[k * G4 + j];
  __syncthreads();
  float s = 0.f;
  for (int k = i; k < Hh; k += 128) s += b1[k] * col[k];
  part[i] = s;
  __syncthreads();
  if (i == 0) {
    float t = bl[j];
    for (int k = 0; k < 128; k++) t += part[k];
    bias2[j] = t;
  }
  float acc = 0.f;
  const float* w1r = W1 + i * Hh;
#pragma unroll 4
  for (int k = 0; k < Hh; k++) acc += w1r[k] * col[k];
  const int gate = j >> 9, r = j & 511, ss = r >> 5, u = r & 31;
  const int c128 = gate * 32 + u, cb = c128 >> 4, c = c128 & 15;
  const int lane = ((i >> 3) & 3) * 16 + c, ks4 = i >> 5, e = i & 7;
  Wc4[((ss * 8 + cb) * 4 + ks4) * 512 + lane * 8 + e] = (_Float16)acc;
}

// ---- W_hh (fp32 [512][2048]) -> f16 B-frags, K-SPLIT layout ---------------
// Whh4[(((ss*8+wv)*8+cb)*2+ks)*512 + lane*8 + e] =
//   W[wv*64 + ks*32 + (lane>>4)*8 + e][gate*512 + ss*32 + u]
//   with c128 = cb*16 + (lane&15), gate = c128>>5, u = c128&31.
__global__ void k_whh(const float* __restrict__ W, _Float16* __restrict__ W4) {
  const int id = blockIdx.x * 256 + threadIdx.x;  // < 131072
  const int lane = id & 63, ks = (id >> 6) & 1, cb = (id >> 7) & 7;
  const int wv = (id >> 10) & 7, ss = id >> 13;
  const int c128 = cb * 16 + (lane & 15);
  const int gate = c128 >> 5, u = c128 & 31;
  const int colg = gate * 512 + ss * 32 + u;
  const int kbase = wv * 64 + ks * 32 + (lane >> 4) * 8;
  h8 o;
#pragma unroll
  for (int e = 0; e < 8; ++e) o[e] = (_Float16)W[(kbase + e) * G4 + colg];
  *(h8*)(W4 + ((((ss * 8 + wv) * 8 + cb) * 2 + ks) * 512) + lane * 8) = o;
}

// ---- persistent scan: 256 WGs = 16 gangs of 16 ----------------------------
__global__ __launch_bounds__(512, 1) void k_scan(
    const float* __restrict__ x, const _Float16* __restrict__ Wc4,
    const float* __restrict__ bias2, const _Float16* __restrict__ Whh4,
    const float* __restrict__ Wo, const float* __restrict__ bo,
    float* __restrict__ out, char* __restrict__ hpub) {
  const int gid = blockIdx.x >> 4, ss = blockIdx.x & 15;
  const int tid = threadIdx.x;
  const int lane = tid & 63, wv = tid >> 6;
  const int l15 = lane & 15, l4 = lane >> 4;

  __shared__ __align__(16) char xws[4096];      // x window [8 rows][128] f16 swizzled
  __shared__ __align__(16) char wots[32768];    // Wo^T [32][512] f16 swizzled
  __shared__ float pre_s[2][2][4][4][33];       // [buf][tt][b][gate][u]
  __shared__ float pgat[8][4][132];             // K-partials [wave][b][c128]
  __shared__ __align__(16) char hopc[2 * 4 * 1056];  // h copy [buf][4 rows][528 f16], XOR-swz
  __shared__ float op_s[32][9];

  // ---- register weights ----------------------------------------------------
  h8 bW[8][2], bC[4];
#pragma unroll
  for (int cb = 0; cb < 8; ++cb)
#pragma unroll
    for (int ks = 0; ks < 2; ++ks)
      bW[cb][ks] = *(const h8*)(Whh4 + ((((ss * 8 + wv) * 8 + cb) * 2 + ks) * 512) + lane * 8);
#pragma unroll
  for (int ks = 0; ks < 4; ++ks)
    bC[ks] = *(const h8*)(Wc4 + ((ss * 8 + wv) * 4 + ks) * 512 + lane * 8);

  const int cb_ = tid >> 5, ml = tid & 31;  // cell role (tid<128): batch=cb_, unit=ml
  const float bI = bias2[ss * 32 + ml],        bF = bias2[512 + ss * 32 + ml],
              bG = bias2[1024 + ss * 32 + ml], bO = bias2[1536 + ss * 32 + ml];
  const float bor = (tid < NS) ? bo[tid] : 0.f;

  // ---- init: zero xws rows 8-15, stage Wo^T --------------------------------
  if (tid < 128) { u32x4 z = {0, 0, 0, 0}; *(u32x4*)(xws + 2048 + tid * 16) = z; }
  for (int it = tid; it < Hh * NS; it += 512) {
    int k = it >> 5, n = it & 31;
    *(_Float16*)(wots + n * 1024 + ((2 * k) ^ ((n & 7) << 4))) = (_Float16)Wo[k * NS + n];
  }
  float c_ = 0.f;

  auto stage_x = [&](int t0) {  // waves 4-5 (tid 256..383): rows tt*4+b
    if (tid >= 256 && tid < 384) {
      const int k = tid - 256, row = k >> 4, cc = k & 15;
      const float* src = x + ((size_t)(gid * BPG + (row & 3)) * Tt + t0 + (row >> 2)) * Ii + cc * 8;
      f4 s0 = *(const f4*)src, s1 = *(const f4*)(src + 4);
      h8 v = {(_Float16)s0[0], (_Float16)s0[1], (_Float16)s0[2], (_Float16)s0[3],
              (_Float16)s1[0], (_Float16)s1[1], (_Float16)s1[2], (_Float16)s1[3]};
      *(h8*)(xws + row * 256 + ((cc * 16) ^ ((row & 7) << 4))) = v;
    }
  };
  auto do_pregate = [&](int buf) {  // all waves, N-split (wave's 16 cols)
    f4 pa = {0.f, 0.f, 0.f, 0.f};
#pragma unroll
    for (int ks = 0; ks < 4; ++ks) {
      const int row = l15;
      h8 a = *(const h8*)(xws + row * 256 + ((ks * 64 + l4 * 16) ^ ((row & 7) << 4)));
      pa = __builtin_amdgcn_mfma_f32_16x16x32_f16(a, bC[ks], pa, 0, 0, 0);
    }
    if (l4 < 2) {
      const int c128 = wv * 16 + l15, gam = c128 >> 5, u = c128 & 31;
#pragma unroll
      for (int e = 0; e < 4; ++e) {
        const int row = l4 * 4 + e;  // 0..7 = tt*4 + b
        pre_s[buf][row >> 2][row & 3][gam][u] = pa[e];
      }
    }
  };
  auto hop_poll = [&](const char* slot, u32 want, int buf) {  // waves 2-3
    if (tid >= 128 && tid < 256) {
      const int k = tid - 128, row = k >> 5, seg = k & 31;
      const u32* p = (const u32*)(slot + (row * 512 + seg * 16) * 4);
      u32x4 v0, v1, v2, v3;
      while (true) {
        asm volatile(
            "global_load_dwordx4 %0, %4, off sc0 sc1\n"
            "global_load_dwordx4 %1, %5, off sc0 sc1\n"
            "global_load_dwordx4 %2, %6, off sc0 sc1\n"
            "global_load_dwordx4 %3, %7, off sc0 sc1\n"
            "s_waitcnt vmcnt(0)"
            : "=&v"(v0), "=&v"(v1), "=&v"(v2), "=&v"(v3)
            : "v"(p), "v"(p + 4), "v"(p + 8), "v"(p + 12)
            : "memory");
        if ((v0[0] >> 16) == want && (v0[1] >> 16) == want &&
            (v0[2] >> 16) == want && (v0[3] >> 16) == want &&
            (v1[0] >> 16) == want && (v1[1] >> 16) == want &&
            (v1[2] >> 16) == want && (v1[3] >> 16) == want &&
            (v2[0] >> 16) == want && (v2[1] >> 16) == want &&
            (v2[2] >> 16) == want && (v2[3] >> 16) == want &&
            (v3[0] >> 16) == want && (v3[1] >> 16) == want &&
            (v3[2] >> 16) == want && (v3[3] >> 16) == want) break;
      }
      __builtin_amdgcn_sched_barrier(0);
      u32x4 w0 = {(v0[0] & 0xffffu) | (v0[1] << 16), (v0[2] & 0xffffu) | (v0[3] << 16),
                  (v1[0] & 0xffffu) | (v1[1] << 16), (v1[2] & 0xffffu) | (v1[3] << 16)};
      u32x4 w1 = {(v2[0] & 0xffffu) | (v2[1] << 16), (v2[2] & 0xffffu) | (v2[3] << 16),
                  (v3[0] & 0xffffu) | (v3[1] << 16), (v3[2] & 0xffffu) | (v3[3] << 16)};
      const int X = ((seg >> 2) & 7) << 4;
      char* base = hopc + buf * 4224 + row * 1056;
      *(u32x4*)(base + ((seg * 32) ^ X)) = w0;
      *(u32x4*)(base + ((seg * 32 + 16) ^ X)) = w1;
    }
  };
  auto opf = [&](int buf) {  // waves 4-7: partials of h[row ss] @ Wo
    if (ss < BPG && tid >= 256) {
      const int k = tid - 256, nn = k & 31, pp = k >> 5;  // pp 0..7
      float acc = 0.f;
#pragma unroll
      for (int q = 0; q < 8; ++q) {
        const int off = pp * 128 + q * 16;
        h8 w_ = *(const h8*)(wots + nn * 1024 + (off ^ ((nn & 7) << 4)));
        h8 hv = *(const h8*)(hopc + buf * 4224 + ss * 1056 + (off ^ ((pp & 7) << 4)));
        acc = dot8(w_, hv, acc);
      }
      op_s[nn][pp] = acc;
    }
  };
  auto out_store = [&](int tindex) {
    if (ss < BPG && tid < NS) {
      float s_ = bor;
#pragma unroll
      for (int p = 0; p < 8; ++p) s_ += op_s[tid][p];
      out[((size_t)(gid * BPG + ss) * Tt + tindex) * NS + tid] = s_;
    }
  };

  stage_x(0);
  __syncthreads();
  do_pregate(0);  // window 0 -> steps 0,1

#pragma unroll 1
  for (int t = 0; t < Tt; ++t) {
    const char* slotP = hpub + gid * 16384 + ((t - 1) & 1) * 8192;  // h_{t-1}, tag t
    char* slotC = hpub + gid * 16384 + (t & 1) * 8192;              // h_t, tag t+1
    // ==== phase 1 ====
    if (t >= 3) out_store(t - 3);
    if (t & 1) { if (t <= 1021) do_pregate(((t + 1) >> 1) & 1); }
    else if (t <= 1020) stage_x(t + 2);
    // gate GEMM K-chunk: poll A-frags into regs, 16 MFMA
    {
      f4 acc[8] = {{0.f,0.f,0.f,0.f},{0.f,0.f,0.f,0.f},{0.f,0.f,0.f,0.f},{0.f,0.f,0.f,0.f},
                   {0.f,0.f,0.f,0.f},{0.f,0.f,0.f,0.f},{0.f,0.f,0.f,0.f},{0.f,0.f,0.f,0.f}};
      if (t > 0) {
        h8 a0 = {}, a1 = {};
        if (l15 < 4) {
          const u32* p = (const u32*)(slotP + (l15 * 512 + wv * 64 + l4 * 8) * 4);
          const u32 want = (u32)t;
          u32x4 v0, v1, v2, v3;
          while (true) {
            asm volatile(
                "global_load_dwordx4 %0, %4, off sc0 sc1\n"
                "global_load_dwordx4 %1, %5, off sc0 sc1\n"
                "global_load_dwordx4 %2, %6, off sc0 sc1\n"
                "global_load_dwordx4 %3, %7, off sc0 sc1\n"
                "s_waitcnt vmcnt(0)"
                : "=&v"(v0), "=&v"(v1), "=&v"(v2), "=&v"(v3)
                : "v"(p), "v"(p + 4), "v"(p + 32), "v"(p + 36)
                : "memory");
            if ((v0[0] >> 16) == want && (v0[1] >> 16) == want &&
                (v0[2] >> 16) == want && (v0[3] >> 16) == want &&
                (v1[0] >> 16) == want && (v1[1] >> 16) == want &&
                (v1[2] >> 16) == want && (v1[3] >> 16) == want &&
                (v2[0] >> 16) == want && (v2[1] >> 16) == want &&
                (v2[2] >> 16) == want && (v2[3] >> 16) == want &&
                (v3[0] >> 16) == want && (v3[1] >> 16) == want &&
                (v3[2] >> 16) == want && (v3[3] >> 16) == want) break;
          }
          __builtin_amdgcn_sched_barrier(0);
          u32x4 w0 = {(v0[0] & 0xffffu) | (v0[1] << 16), (v0[2] & 0xffffu) | (v0[3] << 16),
                      (v1[0] & 0xffffu) | (v1[1] << 16), (v1[2] & 0xffffu) | (v1[3] << 16)};
          u32x4 w1 = {(v2[0] & 0xffffu) | (v2[1] << 16), (v2[2] & 0xffffu) | (v2[3] << 16),
                      (v3[0] & 0xffffu) | (v3[1] << 16), (v3[2] & 0xffffu) | (v3[3] << 16)};
          a0 = __builtin_bit_cast(h8, w0);
          a1 = __builtin_bit_cast(h8, w1);
        }
#pragma unroll
        for (int cb = 0; cb < 8; ++cb) {
          acc[cb] = __builtin_amdgcn_mfma_f32_16x16x32_f16(a0, bW[cb][0], acc[cb], 0, 0, 0);
          acc[cb] = __builtin_amdgcn_mfma_f32_16x16x32_f16(a1, bW[cb][1], acc[cb], 0, 0, 0);
        }
      }
      if (l4 == 0) {
#pragma unroll
        for (int cb = 0; cb < 8; ++cb)
#pragma unroll
          for (int e = 0; e < 4; ++e)
            pgat[wv][e][cb * 16 + l15] = acc[cb][e];
      }
    }
    if (t >= 1) hop_poll(slotP, (u32)t, t & 1);  // h_{t-1} -> hop[t&1]
    __syncthreads();  // B1: pgat + hop ready
    // ==== phase 3 ====
    if (tid < 128) {
      const int b = cb_, u = ml, ph = (t >> 1) & 1, tt = t & 1;
      float s0 = 0.f, s1 = 0.f, s2 = 0.f, s3 = 0.f;
#pragma unroll
      for (int w = 0; w < 8; ++w) {
        s0 += pgat[w][b][u];       s1 += pgat[w][b][32 + u];
        s2 += pgat[w][b][64 + u];  s3 += pgat[w][b][96 + u];
      }
      float aI = s0 + pre_s[ph][tt][b][0][u] + bI;
      float aF = s1 + pre_s[ph][tt][b][1][u] + bF;
      float aG = s2 + pre_s[ph][tt][b][2][u] + bG;
      float aO = s3 + pre_s[ph][tt][b][3][u] + bO;
      float iv = sigf(aI), fv = sigf(aF), gv = __sinf(aG), ov = sigf(aO);
      c_ = fv * c_ + iv * gv;
      float hnv = ov * __sinf(c_);
      _Float16 hf = (_Float16)hnv;
      u32 pkt = (u32)__builtin_bit_cast(unsigned short, hf) | ((u32)(t + 1) << 16);
      u32* dst = (u32*)(slotC + ((size_t)(b * 512 + ss * 32 + u)) * 4);
      asm volatile("global_store_dword %0, %1, off sc0 sc1" :: "v"(dst), "v"(pkt) : "memory");
    }
    if (t >= 2) opf((t - 1) & 1);  // dots of h_{t-2} -> out[t-2] (stored t+1)
    __syncthreads();  // B2
  }
  // ==== epilogue: drain out[1021..1023] ====
  out_store(1021);            // op_s = f(h_1021) from ph3(t=1023)
  __syncthreads();
  opf(1);                     // hop[1] = h_1022
  __syncthreads();
  out_store(1022);
  hop_poll(hpub + gid * 16384 + 8192, (u32)1024, 0);  // h_1023 (slot 1, tag 1024)
  __syncthreads();
  opf(0);
  __syncthreads();
  out_store(1023);
}

extern "C" void kernel_launch(void* const* d_in, const int* in_sizes, int n_in,
                              void* d_out, int out_size, void* d_ws, size_t ws_size,
                              hipStream_t stream) {
  const float* x   = (const float*)d_in[0];
  const float* W1  = (const float*)d_in[1];
  const float* b1  = (const float*)d_in[2];
  const float* Wih = (const float*)d_in[3];
  const float* Whh = (const float*)d_in[4];
  const float* bl  = (const float*)d_in[5];
  const float* Wo  = (const float*)d_in[6];
  const float* bo  = (const float*)d_in[7];
  float* out = (float*)d_out;

  char* ws = (char*)d_ws;
  _Float16* Wc4   = (_Float16*)(ws);            // 512 KB
  float*    bias2 = (float*)(ws + 524288);      // 8 KB
  _Float16* Whh4  = (_Float16*)(ws + 532480);   // 2 MB
  char*     hpub  = ws + 2629632;               // 256 KB (16 gangs x 2 slots x 8KB)

  (void)hipMemsetAsync(hpub, 0, 262144, stream);  // kill stale tags (replay safety)
  k_wc<<<G4, 128, 0, stream>>>(W1, Wih, b1, bl, Wc4, bias2);
  k_whh<<<512, 256, 0, stream>>>(Whh, Whh4);
  k_scan<<<256, 512, 0, stream>>>(x, Wc4, bias2, Whh4, Wo, bo, out, hpub);
}